// Round 2
// baseline (531.570 us; speedup 1.0000x reference)
//
#include <hip/hip_runtime.h>

// MHA forward: x(2,2048,2048) fp32, Wq/Wk/Wv/Wo (2048,2048) fp32 -> out fp32.
// Strategy: cast to bf16, MFMA GEMMs (16x16x32_bf16), flash attention with
// online softmax in fp32, RoPE fused into QKV epilogue, V stored transposed.

#define SEQ 2048
#define DMODEL 2048
#define NH 16
#define HD 128

typedef __attribute__((ext_vector_type(8))) short bf16x8;  // 8 bf16 = 4 VGPRs
typedef __attribute__((ext_vector_type(4))) float f32x4;

__device__ __forceinline__ unsigned short f2bf(float f) {  // RNE fp32->bf16
  unsigned int u = __float_as_uint(f);
  u += 0x7fffu + ((u >> 16) & 1u);
  return (unsigned short)(u >> 16);
}

__device__ __forceinline__ void g2l16(const void* g, void* l) {
  // async global->LDS, 16B/lane; LDS dest must be wave-uniform-base + lane*16
  __builtin_amdgcn_global_load_lds((const __attribute__((address_space(1))) void*)g,
                                   (__attribute__((address_space(3))) void*)l,
                                   16, 0, 0);
}

__device__ __forceinline__ f32x4 mfma16(bf16x8 a, bf16x8 b, f32x4 c) {
  return __builtin_amdgcn_mfma_f32_16x16x32_bf16(a, b, c, 0, 0, 0);
}

// 16-lane butterfly reductions on the VALU pipe via DPP row_ror (0x121+n)
template <int CTRL>
__device__ __forceinline__ float dpp_ror(float v) {
  return __int_as_float(__builtin_amdgcn_mov_dpp(__float_as_int(v), CTRL, 0xf, 0xf, false));
}
__device__ __forceinline__ float red_max16(float v) {
  v = fmaxf(v, dpp_ror<0x128>(v));
  v = fmaxf(v, dpp_ror<0x124>(v));
  v = fmaxf(v, dpp_ror<0x122>(v));
  v = fmaxf(v, dpp_ror<0x121>(v));
  return v;
}
__device__ __forceinline__ float red_sum16(float v) {
  v += dpp_ror<0x128>(v);
  v += dpp_ror<0x124>(v);
  v += dpp_ror<0x122>(v);
  v += dpp_ror<0x121>(v);
  return v;
}

__global__ __launch_bounds__(256) void cvt_kernel(const float* __restrict__ src,
                                                  unsigned short* __restrict__ dst, int n4) {
  int i = blockIdx.x * 256 + threadIdx.x;
  if (i >= n4) return;
  const float4 v = ((const float4*)src)[i];
  ushort4 o;
  o.x = f2bf(v.x); o.y = f2bf(v.y); o.z = f2bf(v.z); o.w = f2bf(v.w);
  ((ushort4*)dst)[i] = o;
}

// ---------------------------------------------------------------------------
// GEMM core: C[m,n] = sum_k A[m,k]*B[n,k] (both row-major, k contiguous).
// 128x128 tile, BK=32, 256 thr = 4 waves, wave = 32 rows x 128 cols.
// LDS layout is k-plane-major: [4 planes of k8][128 rows][8 bf16] -- this is
// lane-contiguous for global_load_lds AND conflict-free for ds_read_b128.
// ---------------------------------------------------------------------------

// z = 0: Q (rope + scale), 1: K (rope), 2: V (store transposed (B,H,hd,S))
__global__ __launch_bounds__(256) void gemm_qkv(
    const unsigned short* __restrict__ X,
    const unsigned short* __restrict__ Wq,
    const unsigned short* __restrict__ Wk,
    const unsigned short* __restrict__ Wv,
    unsigned short* __restrict__ Qo,
    unsigned short* __restrict__ Ko,
    unsigned short* __restrict__ Vo) {
  __shared__ unsigned short As[4 * 128 * 8];
  __shared__ unsigned short Bs[4 * 128 * 8];
  const int z = blockIdx.z;
  const unsigned short* W = (z == 0) ? Wq : (z == 1) ? Wk : Wv;
  const int M0 = blockIdx.y * 128;
  const int h = blockIdx.x;  // one head per column block
  const int N0 = h * 128;
  const int t = threadIdx.x;
  const int w = t >> 6, lane = t & 63, l15 = lane & 15, quad = lane >> 4;

  f32x4 acc[2][8] = {};

  for (int k0 = 0; k0 < DMODEL; k0 += 32) {
    __syncthreads();  // previous tile fully consumed
#pragma unroll
    for (int r = 0; r < 4; ++r) {  // 16 wave-units: 8 for A, 8 for B
      const int u = r * 4 + w;
      const int sub = u & 7, cpl = sub >> 1, hf = sub & 1;
      const int row = hf * 64 + lane;
      if (u < 8)
        g2l16(X + (size_t)(M0 + row) * DMODEL + k0 + cpl * 8, &As[cpl * 1024 + row * 8]);
      else
        g2l16(W + (size_t)(N0 + row) * DMODEL + k0 + cpl * 8, &Bs[cpl * 1024 + row * 8]);
    }
    __syncthreads();  // drains vmcnt -> LDS valid
    bf16x8 af[2];
#pragma unroll
    for (int mt = 0; mt < 2; ++mt)
      af[mt] = *(const bf16x8*)&As[quad * 1024 + (w * 32 + mt * 16 + l15) * 8];
#pragma unroll
    for (int nt = 0; nt < 8; ++nt) {
      const bf16x8 bv = *(const bf16x8*)&Bs[quad * 1024 + (nt * 16 + l15) * 8];
#pragma unroll
      for (int mt = 0; mt < 2; ++mt) acc[mt][nt] = mfma16(af[mt], bv, acc[mt][nt]);
    }
  }

  // Epilogue. C/D layout: col = l15, row = quad*4 + reg.
  if (z < 2) {
    // RoPE: wave covers the full head (cols 0..127), pair d <-> d+64 is
    // acc[mt][jj] <-> acc[mt][jj+4] in the SAME lane/reg.
    const float qscale = (z == 0) ? 0.08838834764831845f : 1.0f;  // 1/sqrt(128)
    float invf[4];
#pragma unroll
    for (int jj = 0; jj < 4; ++jj)
      invf[jj] = exp2f(-0.20762050593046f * (float)(jj * 16 + l15));  // 10000^(-j/64)
    unsigned short* O = (z == 0) ? Qo : Ko;
#pragma unroll
    for (int mt = 0; mt < 2; ++mt)
#pragma unroll
      for (int reg = 0; reg < 4; ++reg) {
        const int m = M0 + w * 32 + mt * 16 + quad * 4 + reg;
        const int b = m >> 11, s = m & 2047;
        unsigned short* ob = O + ((size_t)(b * NH + h) * SEQ + s) * HD;
        const float fs = (float)s;
#pragma unroll
        for (int jj = 0; jj < 4; ++jj) {
          float sn, cs;
          sincosf(fs * invf[jj], &sn, &cs);
          const float x1 = acc[mt][jj][reg], x2 = acc[mt][jj + 4][reg];
          ob[jj * 16 + l15] = f2bf((x1 * cs - x2 * sn) * qscale);
          ob[64 + jj * 16 + l15] = f2bf((x2 * cs + x1 * sn) * qscale);
        }
      }
  } else {
    // V stored transposed: (B,H,hd,S) so attention can stage it key-contiguous
#pragma unroll
    for (int mt = 0; mt < 2; ++mt)
#pragma unroll
      for (int reg = 0; reg < 4; ++reg) {
        const int m = M0 + w * 32 + mt * 16 + quad * 4 + reg;
        const int b = m >> 11, s = m & 2047;
        unsigned short* ob = Vo + (size_t)(b * NH + h) * HD * SEQ;
#pragma unroll
        for (int nt = 0; nt < 8; ++nt)
          ob[(size_t)(nt * 16 + l15) * SEQ + s] = f2bf(acc[mt][nt][reg]);
      }
  }
}

// ---------------------------------------------------------------------------
// Flash attention, causal. Block = 128 q rows x one (b,h); K-tiles of 128.
// Q in registers (A-layout); K,V staged in plane-major LDS via global_load_lds;
// P round-trips through wave-private LDS (reuses K buffer after a barrier).
// ---------------------------------------------------------------------------
__global__ __launch_bounds__(256, 2) void attn_kernel(const unsigned short* __restrict__ Q,
                                                      const unsigned short* __restrict__ K,
                                                      const unsigned short* __restrict__ Vt,
                                                      unsigned short* __restrict__ Oa) {
  __shared__ unsigned short Ks[16 * 128 * 8];  // 32 KB: [hd-plane][key][8]
  __shared__ unsigned short Vs[16 * 128 * 8];  // 32 KB: [key-plane][d][8]
  // grid swizzle: pair (qt) with (15-qt) 256 blocks apart so each CU's two
  // co-resident blocks get a balanced causal workload (17 K-tiles total)
  const int gid = blockIdx.x;
  const int c = gid & 255, phase = gid >> 8;
  const int qt = phase ? 15 - (c & 15) : (c & 15);
  const int bh = phase * 16 + (c >> 4);
  const unsigned short* Qb = Q + (size_t)bh * SEQ * HD;
  const unsigned short* Kb = K + (size_t)bh * SEQ * HD;
  const unsigned short* Vb = Vt + (size_t)bh * HD * SEQ;
  const int t = threadIdx.x;
  const int w = t >> 6, lane = t & 63, l15 = lane & 15, quad = lane >> 4;

  // Q fragments once: A-layout row = l15, k(hd) = ch*32 + quad*8
  bf16x8 qf[2][4];
#pragma unroll
  for (int mt = 0; mt < 2; ++mt)
#pragma unroll
    for (int ch = 0; ch < 4; ++ch)
      qf[mt][ch] = *(const bf16x8*)(Qb + (size_t)(qt * 128 + w * 32 + mt * 16 + l15) * HD +
                                    ch * 32 + quad * 8);

  f32x4 o[2][8] = {};
  float mrow[2][4], lrow[2][4];
#pragma unroll
  for (int mt = 0; mt < 2; ++mt)
#pragma unroll
    for (int reg = 0; reg < 4; ++reg) { mrow[mt][reg] = -1e30f; lrow[mt][reg] = 0.f; }

  for (int kt = 0; kt <= qt; ++kt) {
    __syncthreads();  // previous tile (incl. P region) fully consumed
#pragma unroll
    for (int r = 0; r < 16; ++r) {  // 64 wave-units: 32 K + 32 V
      const int u = r * 4 + w;
      const int sub = u & 31, p = sub >> 1, hf = sub & 1;
      const int row = hf * 64 + lane;
      if (u < 32)
        g2l16(Kb + (size_t)(kt * 128 + row) * HD + p * 8, &Ks[p * 1024 + row * 8]);
      else
        g2l16(Vb + (size_t)row * SEQ + kt * 128 + p * 8, &Vs[p * 1024 + row * 8]);
    }
    __syncthreads();

    // S = Q K^T (Q already scaled by 1/sqrt(hd) in projection epilogue)
    f32x4 s[2][8] = {};
#pragma unroll
    for (int ch = 0; ch < 4; ++ch)
#pragma unroll
      for (int nt = 0; nt < 8; ++nt) {
        const bf16x8 bv = *(const bf16x8*)&Ks[(ch * 4 + quad) * 1024 + (nt * 16 + l15) * 8];
#pragma unroll
        for (int mt = 0; mt < 2; ++mt) s[mt][nt] = mfma16(qf[mt][ch], bv, s[mt][nt]);
      }

    if (kt == qt) {  // causal mask on the diagonal tile
#pragma unroll
      for (int mt = 0; mt < 2; ++mt)
#pragma unroll
        for (int nt = 0; nt < 8; ++nt)
#pragma unroll
          for (int reg = 0; reg < 4; ++reg) {
            const int rr = w * 32 + mt * 16 + quad * 4 + reg;
            const int cc = nt * 16 + l15;
            if (cc > rr) s[mt][nt][reg] = -1e30f;
          }
    }

    // online softmax (fp32); row r = mt*16 + quad*4 + reg, reduce over 16 lanes
#pragma unroll
    for (int mt = 0; mt < 2; ++mt)
#pragma unroll
      for (int reg = 0; reg < 4; ++reg) {
        float vmax = s[mt][0][reg];
#pragma unroll
        for (int nt = 1; nt < 8; ++nt) vmax = fmaxf(vmax, s[mt][nt][reg]);
        vmax = red_max16(vmax);
        const float mo = mrow[mt][reg];
        const float mn = fmaxf(mo, vmax);
        const float alpha = __expf(mo - mn);
        mrow[mt][reg] = mn;
        float rs = 0.f;
#pragma unroll
        for (int nt = 0; nt < 8; ++nt) {
          const float p_ = __expf(s[mt][nt][reg] - mn);
          s[mt][nt][reg] = p_;
          rs += p_;
        }
        rs = red_sum16(rs);
        lrow[mt][reg] = lrow[mt][reg] * alpha + rs;
        // rescale ONLY this row's component (reg), not the whole f32x4
#pragma unroll
        for (int nt = 0; nt < 8; ++nt) o[mt][nt][reg] *= alpha;
      }

    __syncthreads();  // all waves done reading Ks before P overwrites it

    // write P (bf16) into wave-private plane-major region of Ks
    unsigned short* Pw = &Ks[w * 4096];  // [16 key-planes][32 q-rows][8]
#pragma unroll
    for (int mt = 0; mt < 2; ++mt)
#pragma unroll
      for (int nt = 0; nt < 8; ++nt)
#pragma unroll
        for (int reg = 0; reg < 4; ++reg) {
          const int rr = mt * 16 + quad * 4 + reg;
          const int key = nt * 16 + l15;
          Pw[(key >> 3) * 256 + rr * 8 + (key & 7)] = f2bf(s[mt][nt][reg]);
        }

    // O += P V   (same-wave LDS write->read: DS pipe is in-order per wave)
#pragma unroll
    for (int ch = 0; ch < 4; ++ch) {
      bf16x8 pa[2];
#pragma unroll
      for (int mt = 0; mt < 2; ++mt)
        pa[mt] = *(const bf16x8*)&Pw[(ch * 4 + quad) * 256 + (mt * 16 + l15) * 8];
#pragma unroll
      for (int nt = 0; nt < 8; ++nt) {
        const bf16x8 vv = *(const bf16x8*)&Vs[(ch * 4 + quad) * 1024 + (nt * 16 + l15) * 8];
#pragma unroll
        for (int mt = 0; mt < 2; ++mt) o[mt][nt] = mfma16(pa[mt], vv, o[mt][nt]);
      }
    }
  }

  // epilogue: normalize and store attn output as (B*S, D) bf16
  const int b = bh >> 4, h = bh & 15;
#pragma unroll
  for (int mt = 0; mt < 2; ++mt)
#pragma unroll
    for (int reg = 0; reg < 4; ++reg) {
      const int sq = qt * 128 + w * 32 + mt * 16 + quad * 4 + reg;
      const float inv_l = 1.0f / lrow[mt][reg];
      unsigned short* ob = Oa + (size_t)(b * SEQ + sq) * DMODEL + h * HD;
#pragma unroll
      for (int nt = 0; nt < 8; ++nt) ob[nt * 16 + l15] = f2bf(o[mt][nt][reg] * inv_l);
    }
}

// out = attn @ Wo^T, fp32 output
__global__ __launch_bounds__(256) void gemm_out(const unsigned short* __restrict__ A,
                                                const unsigned short* __restrict__ W,
                                                float* __restrict__ out) {
  __shared__ unsigned short As[4 * 128 * 8];
  __shared__ unsigned short Bs[4 * 128 * 8];
  const int M0 = blockIdx.y * 128;
  const int N0 = blockIdx.x * 128;
  const int t = threadIdx.x;
  const int w = t >> 6, lane = t & 63, l15 = lane & 15, quad = lane >> 4;

  f32x4 acc[2][8] = {};

  for (int k0 = 0; k0 < DMODEL; k0 += 32) {
    __syncthreads();
#pragma unroll
    for (int r = 0; r < 4; ++r) {
      const int u = r * 4 + w;
      const int sub = u & 7, cpl = sub >> 1, hf = sub & 1;
      const int row = hf * 64 + lane;
      if (u < 8)
        g2l16(A + (size_t)(M0 + row) * DMODEL + k0 + cpl * 8, &As[cpl * 1024 + row * 8]);
      else
        g2l16(W + (size_t)(N0 + row) * DMODEL + k0 + cpl * 8, &Bs[cpl * 1024 + row * 8]);
    }
    __syncthreads();
    bf16x8 af[2];
#pragma unroll
    for (int mt = 0; mt < 2; ++mt)
      af[mt] = *(const bf16x8*)&As[quad * 1024 + (w * 32 + mt * 16 + l15) * 8];
#pragma unroll
    for (int nt = 0; nt < 8; ++nt) {
      const bf16x8 bv = *(const bf16x8*)&Bs[quad * 1024 + (nt * 16 + l15) * 8];
#pragma unroll
      for (int mt = 0; mt < 2; ++mt) acc[mt][nt] = mfma16(af[mt], bv, acc[mt][nt]);
    }
  }

#pragma unroll
  for (int mt = 0; mt < 2; ++mt)
#pragma unroll
    for (int nt = 0; nt < 8; ++nt)
#pragma unroll
      for (int reg = 0; reg < 4; ++reg) {
        const int m = M0 + w * 32 + mt * 16 + quad * 4 + reg;
        out[(size_t)m * DMODEL + N0 + nt * 16 + l15] = acc[mt][nt][reg];
      }
}

extern "C" void kernel_launch(void* const* d_in, const int* in_sizes, int n_in,
                              void* d_out, int out_size, void* d_ws, size_t ws_size,
                              hipStream_t stream) {
  const float* x = (const float*)d_in[0];
  const float* Wq = (const float*)d_in[1];
  const float* Wk = (const float*)d_in[2];
  const float* Wv = (const float*)d_in[3];
  const float* Wo = (const float*)d_in[4];
  float* out = (float*)d_out;

  const size_t NX = (size_t)2 * SEQ * DMODEL;   // 8388608
  const size_t NW = (size_t)DMODEL * DMODEL;    // 4194304
  unsigned short* ws = (unsigned short*)d_ws;   // total 112 MB of bf16 scratch
  unsigned short* xb = ws;
  unsigned short* wqb = xb + NX;
  unsigned short* wkb = wqb + NW;
  unsigned short* wvb = wkb + NW;
  unsigned short* wob = wvb + NW;
  unsigned short* qb = wob + NW;  // (B,H,S,hd), rope'd + pre-scaled
  unsigned short* kb = qb + NX;   // (B,H,S,hd), rope'd
  unsigned short* vb = kb + NX;   // (B,H,hd,S)  (transposed)
  unsigned short* ab = vb + NX;   // (B*S, D)

  cvt_kernel<<<NX / 1024, 256, 0, stream>>>(x, xb, (int)(NX / 4));
  cvt_kernel<<<NW / 1024, 256, 0, stream>>>(Wq, wqb, (int)(NW / 4));
  cvt_kernel<<<NW / 1024, 256, 0, stream>>>(Wk, wkb, (int)(NW / 4));
  cvt_kernel<<<NW / 1024, 256, 0, stream>>>(Wv, wvb, (int)(NW / 4));
  cvt_kernel<<<NW / 1024, 256, 0, stream>>>(Wo, wob, (int)(NW / 4));

  gemm_qkv<<<dim3(16, 32, 3), 256, 0, stream>>>(xb, wqb, wkb, wvb, qb, kb, vb);
  attn_kernel<<<512, 256, 0, stream>>>(qb, kb, vb, ab);
  gemm_out<<<dim3(16, 32, 1), 256, 0, stream>>>(ab, wob, out);
}

// Round 3
// 442.938 us; speedup vs baseline: 1.2001x; 1.2001x over previous
//
#include <hip/hip_runtime.h>

// MHA forward: x(2,2048,2048) fp32, Wq/Wk/Wv/Wo (2048,2048) fp32 -> out fp32.
// bf16 MFMA GEMMs + flash attention. Staging uses XOR-swizzled row-grouped
// global_load_lds: lane i loads 16B chunk ((i&7)^(row&7)) of row (i>>3) so
// 8 lanes form one contiguous 128B segment (coalesced) while LDS reads stay
// bank-balanced. Fragment reads un-swizzle with chunk^(row&7).

#define SEQ 2048
#define DMODEL 2048
#define NH 16
#define HD 128

typedef __attribute__((ext_vector_type(8))) short bf16x8;  // 8 bf16 = 4 VGPRs
typedef __attribute__((ext_vector_type(4))) float f32x4;

__device__ __forceinline__ unsigned short f2bf(float f) {  // RNE fp32->bf16
  unsigned int u = __float_as_uint(f);
  u += 0x7fffu + ((u >> 16) & 1u);
  return (unsigned short)(u >> 16);
}

__device__ __forceinline__ void g2l16(const void* g, void* l) {
  __builtin_amdgcn_global_load_lds((const __attribute__((address_space(1))) void*)g,
                                   (__attribute__((address_space(3))) void*)l,
                                   16, 0, 0);
}

__device__ __forceinline__ f32x4 mfma16(bf16x8 a, bf16x8 b, f32x4 c) {
  return __builtin_amdgcn_mfma_f32_16x16x32_bf16(a, b, c, 0, 0, 0);
}

template <int CTRL>
__device__ __forceinline__ float dpp_ror(float v) {
  return __int_as_float(__builtin_amdgcn_mov_dpp(__float_as_int(v), CTRL, 0xf, 0xf, false));
}
__device__ __forceinline__ float red_max16(float v) {
  v = fmaxf(v, dpp_ror<0x128>(v));
  v = fmaxf(v, dpp_ror<0x124>(v));
  v = fmaxf(v, dpp_ror<0x122>(v));
  v = fmaxf(v, dpp_ror<0x121>(v));
  return v;
}
__device__ __forceinline__ float red_sum16(float v) {
  v += dpp_ror<0x128>(v);
  v += dpp_ror<0x124>(v);
  v += dpp_ror<0x122>(v);
  v += dpp_ror<0x121>(v);
  return v;
}

// one launch converts x + all four weights (dst regions contiguous in ws)
__global__ __launch_bounds__(256) void cvt_all(const float* __restrict__ x,
                                               const float* __restrict__ wq,
                                               const float* __restrict__ wk,
                                               const float* __restrict__ wv,
                                               const float* __restrict__ wo,
                                               unsigned short* __restrict__ dst0) {
  const int b = blockIdx.x;
  const float* src;
  unsigned short* dst;
  int idx;
  if (b < 8192) {  // x: 2097152 float4's
    src = x; dst = dst0; idx = b * 256 + threadIdx.x;
  } else {
    const int r = (b - 8192) >> 12;  // 4096 blocks per weight
    src = (r == 0) ? wq : (r == 1) ? wk : (r == 2) ? wv : wo;
    dst = dst0 + (size_t)2 * SEQ * DMODEL + (size_t)r * DMODEL * DMODEL;
    idx = ((b - 8192) & 4095) * 256 + threadIdx.x;
  }
  const float4 v = ((const float4*)src)[idx];
  ushort4 o;
  o.x = f2bf(v.x); o.y = f2bf(v.y); o.z = f2bf(v.z); o.w = f2bf(v.w);
  ((ushort4*)dst)[idx] = o;
}

// ---------------------------------------------------------------------------
// GEMM core: C[m,n] = sum_k A[m,k]*B[n,k]. 128x128 tile, BK=64, 4 waves,
// wave = 32 rows x 128 cols. LDS: [row][8 chunks of 8 bf16], chunk position
// swizzled by row&7. Staging: 32 units (16 A + 16 B), 8 rows/unit.
// ---------------------------------------------------------------------------

// z = 0: Q (rope + scale*log2e), 1: K (rope), 2: V (store transposed)
__global__ __launch_bounds__(256) void gemm_qkv(
    const unsigned short* __restrict__ X,
    const unsigned short* __restrict__ Wq,
    const unsigned short* __restrict__ Wk,
    const unsigned short* __restrict__ Wv,
    unsigned short* __restrict__ Qo,
    unsigned short* __restrict__ Ko,
    unsigned short* __restrict__ Vo) {
  __shared__ unsigned short As[128 * 64];  // 16 KB
  __shared__ unsigned short Bs[128 * 64];  // 16 KB
  const int z = blockIdx.z;
  const unsigned short* W = (z == 0) ? Wq : (z == 1) ? Wk : Wv;
  const int M0 = blockIdx.y * 128;
  const int h = blockIdx.x;
  const int N0 = h * 128;
  const int t = threadIdx.x;
  const int w = t >> 6, lane = t & 63, l15 = lane & 15, quad = lane >> 4;
  const int g = lane >> 3, j = lane & 7;
  const int chunk = j ^ g;  // row&7 == g for 8-row-aligned units

  f32x4 acc[2][8] = {};

  for (int k0 = 0; k0 < DMODEL; k0 += 64) {
    __syncthreads();
#pragma unroll
    for (int r = 0; r < 8; ++r) {  // 32 units: 0..15 A, 16..31 B
      const int u = r * 4 + w;
      const int row = (u & 15) * 8 + g;
      if (u < 16)
        g2l16(X + (size_t)(M0 + row) * DMODEL + k0 + chunk * 8, &As[(u & 15) * 512]);
      else
        g2l16(W + (size_t)(N0 + row) * DMODEL + k0 + chunk * 8, &Bs[(u & 15) * 512]);
    }
    __syncthreads();
#pragma unroll
    for (int kc = 0; kc < 2; ++kc) {
      const int c = kc * 4 + quad;
      bf16x8 af[2];
#pragma unroll
      for (int mt = 0; mt < 2; ++mt) {
        const int m = w * 32 + mt * 16 + l15;
        af[mt] = *(const bf16x8*)&As[m * 64 + ((c ^ (m & 7)) << 3)];
      }
#pragma unroll
      for (int nt = 0; nt < 8; ++nt) {
        const int n = nt * 16 + l15;
        const bf16x8 bv = *(const bf16x8*)&Bs[n * 64 + ((c ^ (n & 7)) << 3)];
#pragma unroll
        for (int mt = 0; mt < 2; ++mt) acc[mt][nt] = mfma16(af[mt], bv, acc[mt][nt]);
      }
    }
  }

  // Epilogue. C/D layout: col = l15, row = quad*4 + reg.
  if (z < 2) {
    // Q also pre-multiplied by log2(e)/sqrt(hd) so attention can use exp2
    const float qscale = (z == 0) ? 0.1275174356f : 1.0f;
    float invf[4];
#pragma unroll
    for (int jj = 0; jj < 4; ++jj)
      invf[jj] = exp2f(-0.20762050593046f * (float)(jj * 16 + l15));  // 10000^(-d/64)
    unsigned short* O = (z == 0) ? Qo : Ko;
#pragma unroll
    for (int mt = 0; mt < 2; ++mt)
#pragma unroll
      for (int reg = 0; reg < 4; ++reg) {
        const int m = M0 + w * 32 + mt * 16 + quad * 4 + reg;
        const int b = m >> 11, s = m & 2047;
        unsigned short* ob = O + ((size_t)(b * NH + h) * SEQ + s) * HD;
        const float fs = (float)s;
#pragma unroll
        for (int jj = 0; jj < 4; ++jj) {
          float sn, cs;
          sincosf(fs * invf[jj], &sn, &cs);
          const float x1 = acc[mt][jj][reg], x2 = acc[mt][jj + 4][reg];
          ob[jj * 16 + l15] = f2bf((x1 * cs - x2 * sn) * qscale);
          ob[64 + jj * 16 + l15] = f2bf((x2 * cs + x1 * sn) * qscale);
        }
      }
  } else {
    // V stored transposed: (B,H,hd,S)
#pragma unroll
    for (int mt = 0; mt < 2; ++mt)
#pragma unroll
      for (int reg = 0; reg < 4; ++reg) {
        const int m = M0 + w * 32 + mt * 16 + quad * 4 + reg;
        const int b = m >> 11, s = m & 2047;
        unsigned short* ob = Vo + (size_t)(b * NH + h) * HD * SEQ;
#pragma unroll
        for (int nt = 0; nt < 8; ++nt)
          ob[(size_t)(nt * 16 + l15) * SEQ + s] = f2bf(acc[mt][nt][reg]);
      }
  }
}

// ---------------------------------------------------------------------------
// Flash attention, causal. K/V staged with half-row (128B) swizzle:
// vrow = key*2+half (K) or d*2+half (V); LDS[vrow][8 chunks], chunk pos
// swizzled by (vrow>>1)&7. P round-trips through wave-private LDS.
// ---------------------------------------------------------------------------
__global__ __launch_bounds__(256, 2) void attn_kernel(const unsigned short* __restrict__ Q,
                                                      const unsigned short* __restrict__ K,
                                                      const unsigned short* __restrict__ Vt,
                                                      unsigned short* __restrict__ Oa) {
  __shared__ unsigned short Ks[256 * 64];  // 32 KB
  __shared__ unsigned short Vs[256 * 64];  // 32 KB
  const int gid = blockIdx.x;
  const int c_ = gid & 255, phase = gid >> 8;
  const int qt = phase ? 15 - (c_ & 15) : (c_ & 15);
  const int bh = phase * 16 + (c_ >> 4);
  const unsigned short* Qb = Q + (size_t)bh * SEQ * HD;
  const unsigned short* Kb = K + (size_t)bh * SEQ * HD;
  const unsigned short* Vb = Vt + (size_t)bh * HD * SEQ;
  const int t = threadIdx.x;
  const int w = t >> 6, lane = t & 63, l15 = lane & 15, quad = lane >> 4;
  const int g = lane >> 3, j = lane & 7;

  bf16x8 qf[2][4];
#pragma unroll
  for (int mt = 0; mt < 2; ++mt)
#pragma unroll
    for (int ch = 0; ch < 4; ++ch)
      qf[mt][ch] = *(const bf16x8*)(Qb + (size_t)(qt * 128 + w * 32 + mt * 16 + l15) * HD +
                                    ch * 32 + quad * 8);

  f32x4 o[2][8] = {};
  float mrow[2][4], lrow[2][4];
#pragma unroll
  for (int mt = 0; mt < 2; ++mt)
#pragma unroll
    for (int reg = 0; reg < 4; ++reg) { mrow[mt][reg] = -1e30f; lrow[mt][reg] = 0.f; }

  for (int kt = 0; kt <= qt; ++kt) {
    __syncthreads();
#pragma unroll
    for (int r = 0; r < 16; ++r) {  // 64 units: 32 K + 32 V
      const int u = r * 4 + w;
      if (u < 32) {
        const int vrow = u * 8 + g, key = vrow >> 1;
        const int ck = j ^ (key & 7);
        g2l16(Kb + (size_t)(kt * 128 + key) * HD + (vrow & 1) * 64 + ck * 8, &Ks[u * 512]);
      } else {
        const int u2 = u - 32;
        const int vrow = u2 * 8 + g, d = vrow >> 1;
        const int cv = j ^ (d & 7);
        g2l16(Vb + (size_t)d * SEQ + kt * 128 + (vrow & 1) * 64 + cv * 8, &Vs[u2 * 512]);
      }
    }
    __syncthreads();

    // S = Q K^T (Q pre-scaled by log2e/sqrt(hd))
    f32x4 s[2][8] = {};
#pragma unroll
    for (int ch = 0; ch < 4; ++ch) {
      const int hh = ch >> 1, c = (ch & 1) * 4 + quad;
#pragma unroll
      for (int nt = 0; nt < 8; ++nt) {
        const int n = nt * 16 + l15;
        const bf16x8 bv = *(const bf16x8*)&Ks[(n * 2 + hh) * 64 + ((c ^ (n & 7)) << 3)];
#pragma unroll
        for (int mt = 0; mt < 2; ++mt) s[mt][nt] = mfma16(qf[mt][ch], bv, s[mt][nt]);
      }
    }

    if (kt == qt) {  // causal mask on diagonal tile
#pragma unroll
      for (int mt = 0; mt < 2; ++mt)
#pragma unroll
        for (int nt = 0; nt < 8; ++nt)
#pragma unroll
          for (int reg = 0; reg < 4; ++reg) {
            const int rr = w * 32 + mt * 16 + quad * 4 + reg;
            const int cc = nt * 16 + l15;
            if (cc > rr) s[mt][nt][reg] = -1e30f;
          }
    }

    // online softmax in log2 domain
#pragma unroll
    for (int mt = 0; mt < 2; ++mt)
#pragma unroll
      for (int reg = 0; reg < 4; ++reg) {
        float vmax = s[mt][0][reg];
#pragma unroll
        for (int nt = 1; nt < 8; ++nt) vmax = fmaxf(vmax, s[mt][nt][reg]);
        vmax = red_max16(vmax);
        const float mo = mrow[mt][reg];
        const float mn = fmaxf(mo, vmax);
        const float alpha = exp2f(mo - mn);
        mrow[mt][reg] = mn;
        float rs = 0.f;
#pragma unroll
        for (int nt = 0; nt < 8; ++nt) {
          const float p_ = exp2f(s[mt][nt][reg] - mn);
          s[mt][nt][reg] = p_;
          rs += p_;
        }
        rs = red_sum16(rs);
        lrow[mt][reg] = lrow[mt][reg] * alpha + rs;
#pragma unroll
        for (int nt = 0; nt < 8; ++nt) o[mt][nt][reg] *= alpha;
      }

    __syncthreads();  // all waves done reading Ks before P overwrites it

    unsigned short* Pw = &Ks[w * 4096];  // [16 key-planes][32 q-rows][8]
#pragma unroll
    for (int mt = 0; mt < 2; ++mt)
#pragma unroll
      for (int nt = 0; nt < 8; ++nt)
#pragma unroll
        for (int reg = 0; reg < 4; ++reg) {
          const int rr = mt * 16 + quad * 4 + reg;
          const int key = nt * 16 + l15;
          Pw[(key >> 3) * 256 + rr * 8 + (key & 7)] = f2bf(s[mt][nt][reg]);
        }

    // O += P V
#pragma unroll
    for (int ch = 0; ch < 4; ++ch) {
      const int kh = ch >> 1, c = (ch & 1) * 4 + quad;
      bf16x8 pa[2];
#pragma unroll
      for (int mt = 0; mt < 2; ++mt)
        pa[mt] = *(const bf16x8*)&Pw[(ch * 4 + quad) * 256 + (mt * 16 + l15) * 8];
#pragma unroll
      for (int nt = 0; nt < 8; ++nt) {
        const int d = nt * 16 + l15;
        const bf16x8 vv = *(const bf16x8*)&Vs[(d * 2 + kh) * 64 + ((c ^ (d & 7)) << 3)];
#pragma unroll
        for (int mt = 0; mt < 2; ++mt) o[mt][nt] = mfma16(pa[mt], vv, o[mt][nt]);
      }
    }
  }

  const int b = bh >> 4, h = bh & 15;
#pragma unroll
  for (int mt = 0; mt < 2; ++mt)
#pragma unroll
    for (int reg = 0; reg < 4; ++reg) {
      const int sq = qt * 128 + w * 32 + mt * 16 + quad * 4 + reg;
      const float inv_l = 1.0f / lrow[mt][reg];
      unsigned short* ob = Oa + (size_t)(b * SEQ + sq) * DMODEL + h * HD;
#pragma unroll
      for (int nt = 0; nt < 8; ++nt) ob[nt * 16 + l15] = f2bf(o[mt][nt][reg] * inv_l);
    }
}

// out = attn @ Wo^T, fp32 output
__global__ __launch_bounds__(256) void gemm_out(const unsigned short* __restrict__ A,
                                                const unsigned short* __restrict__ W,
                                                float* __restrict__ out) {
  __shared__ unsigned short As[128 * 64];
  __shared__ unsigned short Bs[128 * 64];
  const int M0 = blockIdx.y * 128;
  const int N0 = blockIdx.x * 128;
  const int t = threadIdx.x;
  const int w = t >> 6, lane = t & 63, l15 = lane & 15, quad = lane >> 4;
  const int g = lane >> 3, j = lane & 7;
  const int chunk = j ^ g;

  f32x4 acc[2][8] = {};

  for (int k0 = 0; k0 < DMODEL; k0 += 64) {
    __syncthreads();
#pragma unroll
    for (int r = 0; r < 8; ++r) {
      const int u = r * 4 + w;
      const int row = (u & 15) * 8 + g;
      if (u < 16)
        g2l16(A + (size_t)(M0 + row) * DMODEL + k0 + chunk * 8, &As[(u & 15) * 512]);
      else
        g2l16(W + (size_t)(N0 + row) * DMODEL + k0 + chunk * 8, &Bs[(u & 15) * 512]);
    }
    __syncthreads();
#pragma unroll
    for (int kc = 0; kc < 2; ++kc) {
      const int c = kc * 4 + quad;
      bf16x8 af[2];
#pragma unroll
      for (int mt = 0; mt < 2; ++mt) {
        const int m = w * 32 + mt * 16 + l15;
        af[mt] = *(const bf16x8*)&As[m * 64 + ((c ^ (m & 7)) << 3)];
      }
#pragma unroll
      for (int nt = 0; nt < 8; ++nt) {
        const int n = nt * 16 + l15;
        const bf16x8 bv = *(const bf16x8*)&Bs[n * 64 + ((c ^ (n & 7)) << 3)];
#pragma unroll
        for (int mt = 0; mt < 2; ++mt) acc[mt][nt] = mfma16(af[mt], bv, acc[mt][nt]);
      }
    }
  }

#pragma unroll
  for (int mt = 0; mt < 2; ++mt)
#pragma unroll
    for (int nt = 0; nt < 8; ++nt)
#pragma unroll
      for (int reg = 0; reg < 4; ++reg) {
        const int m = M0 + w * 32 + mt * 16 + quad * 4 + reg;
        out[(size_t)m * DMODEL + N0 + nt * 16 + l15] = acc[mt][nt][reg];
      }
}

extern "C" void kernel_launch(void* const* d_in, const int* in_sizes, int n_in,
                              void* d_out, int out_size, void* d_ws, size_t ws_size,
                              hipStream_t stream) {
  const float* x = (const float*)d_in[0];
  const float* Wq = (const float*)d_in[1];
  const float* Wk = (const float*)d_in[2];
  const float* Wv = (const float*)d_in[3];
  const float* Wo = (const float*)d_in[4];
  float* out = (float*)d_out;

  const size_t NX = (size_t)2 * SEQ * DMODEL;
  const size_t NW = (size_t)DMODEL * DMODEL;
  unsigned short* ws = (unsigned short*)d_ws;
  unsigned short* xb = ws;
  unsigned short* wqb = xb + NX;
  unsigned short* wkb = wqb + NW;
  unsigned short* wvb = wkb + NW;
  unsigned short* wob = wvb + NW;
  unsigned short* qb = wob + NW;  // (B,H,S,hd), rope'd, scaled by log2e/sqrt(hd)
  unsigned short* kb = qb + NX;   // (B,H,S,hd), rope'd
  unsigned short* vb = kb + NX;   // (B,H,hd,S)
  unsigned short* ab = vb + NX;   // (B*S, D)

  cvt_all<<<24576, 256, 0, stream>>>(x, Wq, Wk, Wv, Wo, ws);
  gemm_qkv<<<dim3(16, 32, 3), 256, 0, stream>>>(xb, wqb, wkb, wvb, qb, kb, vb);
  attn_kernel<<<512, 256, 0, stream>>>(qb, kb, vb, ab);
  gemm_out<<<dim3(16, 32, 1), 256, 0, stream>>>(ab, wob, out);
}

// Round 4
// 411.985 us; speedup vs baseline: 1.2903x; 1.0751x over previous
//
#include <hip/hip_runtime.h>

// MHA forward: x(2,2048,2048) fp32, Wq/Wk/Wv/Wo (2048,2048) fp32 -> out fp32.
// bf16 MFMA GEMMs + flash attention. Staging uses XOR-swizzled row-grouped
// global_load_lds (coalesced 128B segments, bank-balanced LDS reads).
// R3: attn launch_bounds(256) [no min-wave cap -> no register spill];
//     pair-in-block causal balancing: each block does qt=p and qt=15-p
//     (exactly 17 K-tile iterations per block), grid 256.

#define SEQ 2048
#define DMODEL 2048
#define NH 16
#define HD 128

typedef __attribute__((ext_vector_type(8))) short bf16x8;  // 8 bf16 = 4 VGPRs
typedef __attribute__((ext_vector_type(4))) float f32x4;

__device__ __forceinline__ unsigned short f2bf(float f) {  // RNE fp32->bf16
  unsigned int u = __float_as_uint(f);
  u += 0x7fffu + ((u >> 16) & 1u);
  return (unsigned short)(u >> 16);
}

__device__ __forceinline__ void g2l16(const void* g, void* l) {
  __builtin_amdgcn_global_load_lds((const __attribute__((address_space(1))) void*)g,
                                   (__attribute__((address_space(3))) void*)l,
                                   16, 0, 0);
}

__device__ __forceinline__ f32x4 mfma16(bf16x8 a, bf16x8 b, f32x4 c) {
  return __builtin_amdgcn_mfma_f32_16x16x32_bf16(a, b, c, 0, 0, 0);
}

template <int CTRL>
__device__ __forceinline__ float dpp_ror(float v) {
  return __int_as_float(__builtin_amdgcn_mov_dpp(__float_as_int(v), CTRL, 0xf, 0xf, false));
}
__device__ __forceinline__ float red_max16(float v) {
  v = fmaxf(v, dpp_ror<0x128>(v));
  v = fmaxf(v, dpp_ror<0x124>(v));
  v = fmaxf(v, dpp_ror<0x122>(v));
  v = fmaxf(v, dpp_ror<0x121>(v));
  return v;
}
__device__ __forceinline__ float red_sum16(float v) {
  v += dpp_ror<0x128>(v);
  v += dpp_ror<0x124>(v);
  v += dpp_ror<0x122>(v);
  v += dpp_ror<0x121>(v);
  return v;
}

// one launch converts x + all four weights (dst regions contiguous in ws)
__global__ __launch_bounds__(256) void cvt_all(const float* __restrict__ x,
                                               const float* __restrict__ wq,
                                               const float* __restrict__ wk,
                                               const float* __restrict__ wv,
                                               const float* __restrict__ wo,
                                               unsigned short* __restrict__ dst0) {
  const int b = blockIdx.x;
  const float* src;
  unsigned short* dst;
  int idx;
  if (b < 8192) {  // x: 2097152 float4's
    src = x; dst = dst0; idx = b * 256 + threadIdx.x;
  } else {
    const int r = (b - 8192) >> 12;  // 4096 blocks per weight
    src = (r == 0) ? wq : (r == 1) ? wk : (r == 2) ? wv : wo;
    dst = dst0 + (size_t)2 * SEQ * DMODEL + (size_t)r * DMODEL * DMODEL;
    idx = ((b - 8192) & 4095) * 256 + threadIdx.x;
  }
  const float4 v = ((const float4*)src)[idx];
  ushort4 o;
  o.x = f2bf(v.x); o.y = f2bf(v.y); o.z = f2bf(v.z); o.w = f2bf(v.w);
  ((ushort4*)dst)[idx] = o;
}

// ---------------------------------------------------------------------------
// GEMM core: C[m,n] = sum_k A[m,k]*B[n,k]. 128x128 tile, BK=64, 4 waves,
// wave = 32 rows x 128 cols. LDS: [row][8 chunks of 8 bf16], chunk position
// swizzled by row&7. Staging: 32 units (16 A + 16 B), 8 rows/unit.
// ---------------------------------------------------------------------------

// z = 0: Q (rope + scale*log2e), 1: K (rope), 2: V (store transposed)
__global__ __launch_bounds__(256) void gemm_qkv(
    const unsigned short* __restrict__ X,
    const unsigned short* __restrict__ Wq,
    const unsigned short* __restrict__ Wk,
    const unsigned short* __restrict__ Wv,
    unsigned short* __restrict__ Qo,
    unsigned short* __restrict__ Ko,
    unsigned short* __restrict__ Vo) {
  __shared__ unsigned short As[128 * 64];  // 16 KB
  __shared__ unsigned short Bs[128 * 64];  // 16 KB
  const int z = blockIdx.z;
  const unsigned short* W = (z == 0) ? Wq : (z == 1) ? Wk : Wv;
  const int M0 = blockIdx.y * 128;
  const int h = blockIdx.x;
  const int N0 = h * 128;
  const int t = threadIdx.x;
  const int w = t >> 6, lane = t & 63, l15 = lane & 15, quad = lane >> 4;
  const int g = lane >> 3, j = lane & 7;
  const int chunk = j ^ g;  // row&7 == g for 8-row-aligned units

  f32x4 acc[2][8] = {};

  for (int k0 = 0; k0 < DMODEL; k0 += 64) {
    __syncthreads();
#pragma unroll
    for (int r = 0; r < 8; ++r) {  // 32 units: 0..15 A, 16..31 B
      const int u = r * 4 + w;
      const int row = (u & 15) * 8 + g;
      if (u < 16)
        g2l16(X + (size_t)(M0 + row) * DMODEL + k0 + chunk * 8, &As[(u & 15) * 512]);
      else
        g2l16(W + (size_t)(N0 + row) * DMODEL + k0 + chunk * 8, &Bs[(u & 15) * 512]);
    }
    __syncthreads();
#pragma unroll
    for (int kc = 0; kc < 2; ++kc) {
      const int c = kc * 4 + quad;
      bf16x8 af[2];
#pragma unroll
      for (int mt = 0; mt < 2; ++mt) {
        const int m = w * 32 + mt * 16 + l15;
        af[mt] = *(const bf16x8*)&As[m * 64 + ((c ^ (m & 7)) << 3)];
      }
#pragma unroll
      for (int nt = 0; nt < 8; ++nt) {
        const int n = nt * 16 + l15;
        const bf16x8 bv = *(const bf16x8*)&Bs[n * 64 + ((c ^ (n & 7)) << 3)];
#pragma unroll
        for (int mt = 0; mt < 2; ++mt) acc[mt][nt] = mfma16(af[mt], bv, acc[mt][nt]);
      }
    }
  }

  // Epilogue. C/D layout: col = l15, row = quad*4 + reg.
  if (z < 2) {
    // Q also pre-multiplied by log2(e)/sqrt(hd) so attention can use exp2
    const float qscale = (z == 0) ? 0.1275174356f : 1.0f;
    float invf[4];
#pragma unroll
    for (int jj = 0; jj < 4; ++jj)
      invf[jj] = exp2f(-0.20762050593046f * (float)(jj * 16 + l15));  // 10000^(-d/64)
    unsigned short* O = (z == 0) ? Qo : Ko;
#pragma unroll
    for (int mt = 0; mt < 2; ++mt)
#pragma unroll
      for (int reg = 0; reg < 4; ++reg) {
        const int m = M0 + w * 32 + mt * 16 + quad * 4 + reg;
        const int b = m >> 11, s = m & 2047;
        unsigned short* ob = O + ((size_t)(b * NH + h) * SEQ + s) * HD;
        const float fs = (float)s;
#pragma unroll
        for (int jj = 0; jj < 4; ++jj) {
          float sn, cs;
          sincosf(fs * invf[jj], &sn, &cs);
          const float x1 = acc[mt][jj][reg], x2 = acc[mt][jj + 4][reg];
          ob[jj * 16 + l15] = f2bf((x1 * cs - x2 * sn) * qscale);
          ob[64 + jj * 16 + l15] = f2bf((x2 * cs + x1 * sn) * qscale);
        }
      }
  } else {
    // V stored transposed: (B,H,hd,S)
#pragma unroll
    for (int mt = 0; mt < 2; ++mt)
#pragma unroll
      for (int reg = 0; reg < 4; ++reg) {
        const int m = M0 + w * 32 + mt * 16 + quad * 4 + reg;
        const int b = m >> 11, s = m & 2047;
        unsigned short* ob = Vo + (size_t)(b * NH + h) * HD * SEQ;
#pragma unroll
        for (int nt = 0; nt < 8; ++nt)
          ob[(size_t)(nt * 16 + l15) * SEQ + s] = f2bf(acc[mt][nt][reg]);
      }
  }
}

// ---------------------------------------------------------------------------
// Flash attention, causal. Block = one (b,h), processes q-tiles p and 15-p
// sequentially: exactly 17 K-tile iterations per block (perfect balance).
// K/V staged with half-row (128B) swizzle. P round-trips through
// wave-private LDS. No min-wave launch bound -> no register spill.
// ---------------------------------------------------------------------------
__global__ __launch_bounds__(256) void attn_kernel(const unsigned short* __restrict__ Q,
                                                   const unsigned short* __restrict__ K,
                                                   const unsigned short* __restrict__ Vt,
                                                   unsigned short* __restrict__ Oa) {
  __shared__ unsigned short Ks[256 * 64];  // 32 KB
  __shared__ unsigned short Vs[256 * 64];  // 32 KB
  const int gid = blockIdx.x;
  const int bh = gid & 31;   // bh = XCD-local: each XCD caches 4 bh's K+V (4MB)
  const int pr = gid >> 5;   // pair index 0..7
  const unsigned short* Qb = Q + (size_t)bh * SEQ * HD;
  const unsigned short* Kb = K + (size_t)bh * SEQ * HD;
  const unsigned short* Vb = Vt + (size_t)bh * HD * SEQ;
  const int t = threadIdx.x;
  const int w = t >> 6, lane = t & 63, l15 = lane & 15, quad = lane >> 4;
  const int g = lane >> 3, j = lane & 7;
  const int b = bh >> 4, h = bh & 15;

  for (int half = 0; half < 2; ++half) {
    const int qt = half ? 15 - pr : pr;

    // Q fragments: A-layout row = l15, k(hd) = ch*32 + quad*8
    bf16x8 qf[2][4];
#pragma unroll
    for (int mt = 0; mt < 2; ++mt)
#pragma unroll
      for (int ch = 0; ch < 4; ++ch)
        qf[mt][ch] = *(const bf16x8*)(Qb + (size_t)(qt * 128 + w * 32 + mt * 16 + l15) * HD +
                                      ch * 32 + quad * 8);

    f32x4 o[2][8] = {};
    float mrow[2][4], lrow[2][4];
#pragma unroll
    for (int mt = 0; mt < 2; ++mt)
#pragma unroll
      for (int reg = 0; reg < 4; ++reg) { mrow[mt][reg] = -1e30f; lrow[mt][reg] = 0.f; }

    for (int kt = 0; kt <= qt; ++kt) {
      __syncthreads();
#pragma unroll
      for (int r = 0; r < 16; ++r) {  // 64 units: 32 K + 32 V
        const int u = r * 4 + w;
        if (u < 32) {
          const int vrow = u * 8 + g, key = vrow >> 1;
          const int ck = j ^ (key & 7);
          g2l16(Kb + (size_t)(kt * 128 + key) * HD + (vrow & 1) * 64 + ck * 8, &Ks[u * 512]);
        } else {
          const int u2 = u - 32;
          const int vrow = u2 * 8 + g, d = vrow >> 1;
          const int cv = j ^ (d & 7);
          g2l16(Vb + (size_t)d * SEQ + kt * 128 + (vrow & 1) * 64 + cv * 8, &Vs[u2 * 512]);
        }
      }
      __syncthreads();

      // S = Q K^T (Q pre-scaled by log2e/sqrt(hd))
      f32x4 s[2][8] = {};
#pragma unroll
      for (int ch = 0; ch < 4; ++ch) {
        const int hh = ch >> 1, c = (ch & 1) * 4 + quad;
#pragma unroll
        for (int nt = 0; nt < 8; ++nt) {
          const int n = nt * 16 + l15;
          const bf16x8 bv = *(const bf16x8*)&Ks[(n * 2 + hh) * 64 + ((c ^ (n & 7)) << 3)];
#pragma unroll
          for (int mt = 0; mt < 2; ++mt) s[mt][nt] = mfma16(qf[mt][ch], bv, s[mt][nt]);
        }
      }

      if (kt == qt) {  // causal mask on diagonal tile
#pragma unroll
        for (int mt = 0; mt < 2; ++mt)
#pragma unroll
          for (int nt = 0; nt < 8; ++nt)
#pragma unroll
            for (int reg = 0; reg < 4; ++reg) {
              const int rr = w * 32 + mt * 16 + quad * 4 + reg;
              const int cc = nt * 16 + l15;
              if (cc > rr) s[mt][nt][reg] = -1e30f;
            }
      }

      // online softmax in log2 domain
#pragma unroll
      for (int mt = 0; mt < 2; ++mt)
#pragma unroll
        for (int reg = 0; reg < 4; ++reg) {
          float vmax = s[mt][0][reg];
#pragma unroll
          for (int nt = 1; nt < 8; ++nt) vmax = fmaxf(vmax, s[mt][nt][reg]);
          vmax = red_max16(vmax);
          const float mo = mrow[mt][reg];
          const float mn = fmaxf(mo, vmax);
          const float alpha = exp2f(mo - mn);
          mrow[mt][reg] = mn;
          float rs = 0.f;
#pragma unroll
          for (int nt = 0; nt < 8; ++nt) {
            const float p_ = exp2f(s[mt][nt][reg] - mn);
            s[mt][nt][reg] = p_;
            rs += p_;
          }
          rs = red_sum16(rs);
          lrow[mt][reg] = lrow[mt][reg] * alpha + rs;
#pragma unroll
          for (int nt = 0; nt < 8; ++nt) o[mt][nt][reg] *= alpha;
        }

      __syncthreads();  // all waves done reading Ks before P overwrites it

      unsigned short* Pw = &Ks[w * 4096];  // [16 key-planes][32 q-rows][8]
#pragma unroll
      for (int mt = 0; mt < 2; ++mt)
#pragma unroll
        for (int nt = 0; nt < 8; ++nt)
#pragma unroll
          for (int reg = 0; reg < 4; ++reg) {
            const int rr = mt * 16 + quad * 4 + reg;
            const int key = nt * 16 + l15;
            Pw[(key >> 3) * 256 + rr * 8 + (key & 7)] = f2bf(s[mt][nt][reg]);
          }

      // O += P V
#pragma unroll
      for (int ch = 0; ch < 4; ++ch) {
        const int kh = ch >> 1, c = (ch & 1) * 4 + quad;
        bf16x8 pa[2];
#pragma unroll
        for (int mt = 0; mt < 2; ++mt)
          pa[mt] = *(const bf16x8*)&Pw[(ch * 4 + quad) * 256 + (mt * 16 + l15) * 8];
#pragma unroll
        for (int nt = 0; nt < 8; ++nt) {
          const int d = nt * 16 + l15;
          const bf16x8 vv = *(const bf16x8*)&Vs[(d * 2 + kh) * 64 + ((c ^ (d & 7)) << 3)];
#pragma unroll
          for (int mt = 0; mt < 2; ++mt) o[mt][nt] = mfma16(pa[mt], vv, o[mt][nt]);
        }
      }
    }

    // epilogue: normalize and store attn output as (B*S, D) bf16
#pragma unroll
    for (int mt = 0; mt < 2; ++mt)
#pragma unroll
      for (int reg = 0; reg < 4; ++reg) {
        const int sq = qt * 128 + w * 32 + mt * 16 + quad * 4 + reg;
        const float inv_l = 1.0f / lrow[mt][reg];
        unsigned short* ob = Oa + (size_t)(b * SEQ + sq) * DMODEL + h * HD;
#pragma unroll
        for (int nt = 0; nt < 8; ++nt) ob[nt * 16 + l15] = f2bf(o[mt][nt][reg] * inv_l);
      }
  }
}

// out = attn @ Wo^T, fp32 output
__global__ __launch_bounds__(256) void gemm_out(const unsigned short* __restrict__ A,
                                                const unsigned short* __restrict__ W,
                                                float* __restrict__ out) {
  __shared__ unsigned short As[128 * 64];
  __shared__ unsigned short Bs[128 * 64];
  const int M0 = blockIdx.y * 128;
  const int N0 = blockIdx.x * 128;
  const int t = threadIdx.x;
  const int w = t >> 6, lane = t & 63, l15 = lane & 15, quad = lane >> 4;
  const int g = lane >> 3, j = lane & 7;
  const int chunk = j ^ g;

  f32x4 acc[2][8] = {};

  for (int k0 = 0; k0 < DMODEL; k0 += 64) {
    __syncthreads();
#pragma unroll
    for (int r = 0; r < 8; ++r) {
      const int u = r * 4 + w;
      const int row = (u & 15) * 8 + g;
      if (u < 16)
        g2l16(A + (size_t)(M0 + row) * DMODEL + k0 + chunk * 8, &As[(u & 15) * 512]);
      else
        g2l16(W + (size_t)(N0 + row) * DMODEL + k0 + chunk * 8, &Bs[(u & 15) * 512]);
    }
    __syncthreads();
#pragma unroll
    for (int kc = 0; kc < 2; ++kc) {
      const int c = kc * 4 + quad;
      bf16x8 af[2];
#pragma unroll
      for (int mt = 0; mt < 2; ++mt) {
        const int m = w * 32 + mt * 16 + l15;
        af[mt] = *(const bf16x8*)&As[m * 64 + ((c ^ (m & 7)) << 3)];
      }
#pragma unroll
      for (int nt = 0; nt < 8; ++nt) {
        const int n = nt * 16 + l15;
        const bf16x8 bv = *(const bf16x8*)&Bs[n * 64 + ((c ^ (n & 7)) << 3)];
#pragma unroll
        for (int mt = 0; mt < 2; ++mt) acc[mt][nt] = mfma16(af[mt], bv, acc[mt][nt]);
      }
    }
  }

#pragma unroll
  for (int mt = 0; mt < 2; ++mt)
#pragma unroll
    for (int nt = 0; nt < 8; ++nt)
#pragma unroll
      for (int reg = 0; reg < 4; ++reg) {
        const int m = M0 + w * 32 + mt * 16 + quad * 4 + reg;
        out[(size_t)m * DMODEL + N0 + nt * 16 + l15] = acc[mt][nt][reg];
      }
}

extern "C" void kernel_launch(void* const* d_in, const int* in_sizes, int n_in,
                              void* d_out, int out_size, void* d_ws, size_t ws_size,
                              hipStream_t stream) {
  const float* x = (const float*)d_in[0];
  const float* Wq = (const float*)d_in[1];
  const float* Wk = (const float*)d_in[2];
  const float* Wv = (const float*)d_in[3];
  const float* Wo = (const float*)d_in[4];
  float* out = (float*)d_out;

  const size_t NX = (size_t)2 * SEQ * DMODEL;
  const size_t NW = (size_t)DMODEL * DMODEL;
  unsigned short* ws = (unsigned short*)d_ws;
  unsigned short* xb = ws;
  unsigned short* wqb = xb + NX;
  unsigned short* wkb = wqb + NW;
  unsigned short* wvb = wkb + NW;
  unsigned short* wob = wvb + NW;
  unsigned short* qb = wob + NW;  // (B,H,S,hd), rope'd, scaled by log2e/sqrt(hd)
  unsigned short* kb = qb + NX;   // (B,H,S,hd), rope'd
  unsigned short* vb = kb + NX;   // (B,H,hd,S)
  unsigned short* ab = vb + NX;   // (B*S, D)

  cvt_all<<<24576, 256, 0, stream>>>(x, Wq, Wk, Wv, Wo, ws);
  gemm_qkv<<<dim3(16, 32, 3), 256, 0, stream>>>(xb, wqb, wkb, wvb, qb, kb, vb);
  attn_kernel<<<256, 256, 0, stream>>>(qb, kb, vb, ab);
  gemm_out<<<dim3(16, 32, 1), 256, 0, stream>>>(ab, wob, out);
}